// Round 7
// baseline (248.089 us; speedup 1.0000x reference)
//
#include <hip/hip_runtime.h>

#define DIM 4096
#define RPB 16     // kernel 1: rows per block per matrix; grid = DIM/RPB = 256 (1 block/CU)
#define BLK1 768   // 12 waves = 3 matrices x 4 waves; each wave does 4 rows
#define BLK2 512   // kernel 2: 8 waves; each wave does 2 rows; grid = DIM/16 = 256

typedef float f4 __attribute__((ext_vector_type(4)));

__device__ __forceinline__ float dot4(f4 a, f4 b) {
  return a[0] * b[0] + a[1] * b[1] + a[2] * b[2] + a[3] * b[3];
}

// token-mix: x*m + s*(1-m) == s + (x-s)*m
__device__ __forceinline__ f4 mix4(f4 xi, f4 si, f4 m) {
  f4 r;
  r[0] = fmaf(xi[0] - si[0], m[0], si[0]);
  r[1] = fmaf(xi[1] - si[1], m[1], si[1]);
  r[2] = fmaf(xi[2] - si[2], m[2], si[2]);
  r[3] = fmaf(xi[3] - si[3], m[3], si[3]);
  return r;
}

// ---------- kernel 1: stage mixed-x in LDS, 4-rows-per-wave 3-way matvec, WKV epilogue ----------
// grid = 256 blocks (1/CU); __launch_bounds__(768,3) -> ~170 VGPR cap for deep load pipelining
__global__ void __launch_bounds__(BLK1, 3) fused3_kernel(
    const float* __restrict__ x, const float* __restrict__ sxx,
    const float* __restrict__ tmk, const float* __restrict__ tmv,
    const float* __restrict__ tmr,
    const float* __restrict__ wrec, const float* __restrict__ wkey,
    const float* __restrict__ wval,
    const float* __restrict__ aa, const float* __restrict__ bb,
    const float* __restrict__ pp,
    const float* __restrict__ t_decay, const float* __restrict__ t_first,
    float* __restrict__ rab, float* __restrict__ out_x,
    float* __restrict__ out_aa, float* __restrict__ out_bb,
    float* __restrict__ out_pp) {
  __shared__ f4 xmix[3][DIM / 4];  // 48 KB: [0]=xr, [1]=xk, [2]=xv
  __shared__ float red[3][RPB];

  const int t = threadIdx.x;

  const f4* x4  = (const f4*)x;
  const f4* s4  = (const f4*)sxx;
  const f4* mk4 = (const f4*)tmk;
  const f4* mv4 = (const f4*)tmv;
  const f4* mr4 = (const f4*)tmr;

  // cooperative staging of the three mixed vectors (1024 f4 over 768 threads)
  for (int idx = t; idx < DIM / 4; idx += BLK1) {
    f4 xi = x4[idx], si = s4[idx];
    xmix[0][idx] = mix4(xi, si, mr4[idx]);
    xmix[1][idx] = mix4(xi, si, mk4[idx]);
    xmix[2][idx] = mix4(xi, si, mv4[idx]);
  }
  __syncthreads();

  const int wave = t >> 6, lane = t & 63;
  const int mat = wave >> 2;   // 0..2
  const int wr  = wave & 3;    // 0..3
  const int row0 = blockIdx.x * RPB + 4 * wr;

  const float* wbase = (mat == 0) ? wrec : ((mat == 1) ? wkey : wval);
  const f4* wp0 = (const f4*)(wbase + (size_t)(row0 + 0) * DIM);
  const f4* wp1 = (const f4*)(wbase + (size_t)(row0 + 1) * DIM);
  const f4* wp2 = (const f4*)(wbase + (size_t)(row0 + 2) * DIM);
  const f4* wp3 = (const f4*)(wbase + (size_t)(row0 + 3) * DIM);
  const f4* xp = xmix[mat];

  // four independent 16-deep load streams per wave (64 KB contiguous per wave)
  float acc0 = 0.f, acc1 = 0.f, acc2 = 0.f, acc3 = 0.f;
#pragma unroll
  for (int i = 0; i < 16; ++i) {
    f4 w0 = __builtin_nontemporal_load(&wp0[i * 64 + lane]);
    f4 w1 = __builtin_nontemporal_load(&wp1[i * 64 + lane]);
    f4 w2 = __builtin_nontemporal_load(&wp2[i * 64 + lane]);
    f4 w3 = __builtin_nontemporal_load(&wp3[i * 64 + lane]);
    f4 xv = xp[i * 64 + lane];
    acc0 += dot4(w0, xv);
    acc1 += dot4(w1, xv);
    acc2 += dot4(w2, xv);
    acc3 += dot4(w3, xv);
  }

#pragma unroll
  for (int off = 32; off > 0; off >>= 1) {
    acc0 += __shfl_down(acc0, off);
    acc1 += __shfl_down(acc1, off);
    acc2 += __shfl_down(acc2, off);
    acc3 += __shfl_down(acc3, off);
  }
  if (lane == 0) {
    red[mat][4 * wr + 0] = acc0;
    red[mat][4 * wr + 1] = acc1;
    red[mat][4 * wr + 2] = acc2;
    red[mat][4 * wr + 3] = acc3;
  }
  __syncthreads();

  if (t < RPB) {
    const int orow = blockIdx.x * RPB + t;
    float sr = red[0][t];
    float sk = red[1][t];
    float sv = red[2][t];

    float rsig = 1.0f / (1.0f + expf(-sr));
    float ppi = pp[orow], aai = aa[orow], bbi = bb[orow];
    // output path (bonus t_first)
    float ww = t_first[orow] + sk;
    float p  = fmaxf(ppi, ww);
    float e1 = expf(ppi - p), e2 = expf(ww - p);
    float a = e1 * aai + e2 * sv;
    float b = e1 * bbi + e2;
    rab[orow] = rsig * (a / b);
    // state update path (decay)
    float ww2 = ppi + t_decay[orow];
    float p2  = fmaxf(ww2, sk);
    float e1b = expf(ww2 - p2), e2b = expf(sk - p2);
    out_x[orow]  = x[orow];
    out_aa[orow] = e1b * aai + e2b * sv;
    out_bb[orow] = e1b * bbi + e2b;
    out_pp[orow] = p2;
  }
}

// ---------- kernel 2: y = w_out @ rab, 2 rows per wave, rab staged in LDS ----------
// __launch_bounds__(512,2) -> 256 VGPR cap: all 32 loads of the unrolled loop can be in flight
__global__ void __launch_bounds__(BLK2, 2) matvec_out_kernel(
    const float* __restrict__ w, const float* __restrict__ xin,
    float* __restrict__ y) {
  __shared__ f4 xs[DIM / 4];  // 16 KB
  const int t = threadIdx.x;
  const f4* x4 = (const f4*)xin;
#pragma unroll
  for (int k = 0; k < 2; ++k) xs[t + k * BLK2] = x4[t + k * BLK2];
  __syncthreads();

  const int wave = t >> 6, lane = t & 63;  // 8 waves
  const int rowA = blockIdx.x * 16 + 2 * wave;
  const int rowB = rowA + 1;
  const f4* wpA = (const f4*)(w + (size_t)rowA * DIM);
  const f4* wpB = (const f4*)(w + (size_t)rowB * DIM);

  float accA = 0.f, accB = 0.f;
#pragma unroll
  for (int i = 0; i < 16; ++i) {
    f4 wa = __builtin_nontemporal_load(&wpA[i * 64 + lane]);
    f4 wb = __builtin_nontemporal_load(&wpB[i * 64 + lane]);
    f4 xv = xs[i * 64 + lane];
    accA += dot4(wa, xv);
    accB += dot4(wb, xv);
  }

#pragma unroll
  for (int off = 32; off > 0; off >>= 1) {
    accA += __shfl_down(accA, off);
    accB += __shfl_down(accB, off);
  }
  if (lane == 0) {
    y[rowA] = accA;
    y[rowB] = accB;
  }
}

extern "C" void kernel_launch(void* const* d_in, const int* in_sizes, int n_in,
                              void* d_out, int out_size, void* d_ws, size_t ws_size,
                              hipStream_t stream) {
  const float* x       = (const float*)d_in[0];
  const float* sxx     = (const float*)d_in[1];
  const float* aa      = (const float*)d_in[2];
  const float* bb      = (const float*)d_in[3];
  const float* pp      = (const float*)d_in[4];
  const float* w_key   = (const float*)d_in[5];
  const float* w_val   = (const float*)d_in[6];
  const float* w_rec   = (const float*)d_in[7];
  const float* w_out   = (const float*)d_in[8];
  const float* t_decay = (const float*)d_in[9];
  const float* t_first = (const float*)d_in[10];
  const float* t_mix_k = (const float*)d_in[11];
  const float* t_mix_v = (const float*)d_in[12];
  const float* t_mix_r = (const float*)d_in[13];

  float* out    = (float*)d_out;
  float* y      = out;            // output 0
  float* out_x  = out + DIM;      // output 1 (new state_xx = x)
  float* out_aa = out + 2 * DIM;  // output 2
  float* out_bb = out + 3 * DIM;  // output 3
  float* out_pp = out + 4 * DIM;  // output 4

  float* rab = (float*)d_ws;      // 4096 floats

  fused3_kernel<<<DIM / RPB, BLK1, 0, stream>>>(
      x, sxx, t_mix_k, t_mix_v, t_mix_r, w_rec, w_key, w_val,
      aa, bb, pp, t_decay, t_first,
      rab, out_x, out_aa, out_bb, out_pp);
  matvec_out_kernel<<<DIM / 16, BLK2, 0, stream>>>(w_out, rab, y);
}

// Round 8
// 235.230 us; speedup vs baseline: 1.0547x; 1.0547x over previous
//
#include <hip/hip_runtime.h>

#define DIM 4096
#define RPB 8      // rows per block (per matrix) in kernel 1; grid = DIM/RPB = 512
#define BLK1 768   // 12 waves = 3 matrices x 4 waves; each wave does 2 rows
#define BLK2 256   // kernel 2: 4 waves, one row each

typedef float f4 __attribute__((ext_vector_type(4)));

__device__ __forceinline__ float dot4(f4 a, f4 b) {
  return a[0] * b[0] + a[1] * b[1] + a[2] * b[2] + a[3] * b[3];
}

// token-mix: x*m + s*(1-m) == s + (x-s)*m
__device__ __forceinline__ f4 mix4(f4 xi, f4 si, f4 m) {
  f4 r;
  r[0] = fmaf(xi[0] - si[0], m[0], si[0]);
  r[1] = fmaf(xi[1] - si[1], m[1], si[1]);
  r[2] = fmaf(xi[2] - si[2], m[2], si[2]);
  r[3] = fmaf(xi[3] - si[3], m[3], si[3]);
  return r;
}

// ---------- kernel 1: stage mixed-x in LDS, 2-rows-per-wave 3-way matvec, WKV epilogue ----------
__global__ void __launch_bounds__(BLK1, 6) fused3_kernel(
    const float* __restrict__ x, const float* __restrict__ sxx,
    const float* __restrict__ tmk, const float* __restrict__ tmv,
    const float* __restrict__ tmr,
    const float* __restrict__ wrec, const float* __restrict__ wkey,
    const float* __restrict__ wval,
    const float* __restrict__ aa, const float* __restrict__ bb,
    const float* __restrict__ pp,
    const float* __restrict__ t_decay, const float* __restrict__ t_first,
    float* __restrict__ rab, float* __restrict__ out_x,
    float* __restrict__ out_aa, float* __restrict__ out_bb,
    float* __restrict__ out_pp) {
  __shared__ f4 xmix[3][DIM / 4];  // 48 KB: [0]=xr, [1]=xk, [2]=xv
  __shared__ float red[3][RPB];

  const int t = threadIdx.x;

  const f4* x4  = (const f4*)x;
  const f4* s4  = (const f4*)sxx;
  const f4* mk4 = (const f4*)tmk;
  const f4* mv4 = (const f4*)tmv;
  const f4* mr4 = (const f4*)tmr;

  // cooperative staging of the three mixed vectors (1024 f4 over 768 threads)
  for (int idx = t; idx < DIM / 4; idx += BLK1) {
    f4 xi = x4[idx], si = s4[idx];
    xmix[0][idx] = mix4(xi, si, mr4[idx]);
    xmix[1][idx] = mix4(xi, si, mk4[idx]);
    xmix[2][idx] = mix4(xi, si, mv4[idx]);
  }
  __syncthreads();

  const int wave = t >> 6, lane = t & 63;
  const int mat = wave >> 2;   // 0..2
  const int wr  = wave & 3;    // 0..3
  const int rowA = blockIdx.x * RPB + 2 * wr;
  const int rowB = rowA + 1;

  const float* wbase = (mat == 0) ? wrec : ((mat == 1) ? wkey : wval);
  const f4* wpA = (const f4*)(wbase + (size_t)rowA * DIM);
  const f4* wpB = (const f4*)(wbase + (size_t)rowB * DIM);
  const f4* xp = xmix[mat];

  // two independent 16-deep load streams per wave (32 KB contiguous per wave)
  float accA = 0.f, accB = 0.f;
#pragma unroll
  for (int i = 0; i < 16; ++i) {
    f4 wa = __builtin_nontemporal_load(&wpA[i * 64 + lane]);
    f4 wb = __builtin_nontemporal_load(&wpB[i * 64 + lane]);
    f4 xv = xp[i * 64 + lane];
    accA += dot4(wa, xv);
    accB += dot4(wb, xv);
  }

#pragma unroll
  for (int off = 32; off > 0; off >>= 1) {
    accA += __shfl_down(accA, off);
    accB += __shfl_down(accB, off);
  }
  if (lane == 0) {
    red[mat][2 * wr]     = accA;
    red[mat][2 * wr + 1] = accB;
  }
  __syncthreads();

  if (t < RPB) {
    const int orow = blockIdx.x * RPB + t;
    float sr = red[0][t];
    float sk = red[1][t];
    float sv = red[2][t];

    float rsig = 1.0f / (1.0f + expf(-sr));
    float ppi = pp[orow], aai = aa[orow], bbi = bb[orow];
    // output path (bonus t_first)
    float ww = t_first[orow] + sk;
    float p  = fmaxf(ppi, ww);
    float e1 = expf(ppi - p), e2 = expf(ww - p);
    float a = e1 * aai + e2 * sv;
    float b = e1 * bbi + e2;
    rab[orow] = rsig * (a / b);
    // state update path (decay)
    float ww2 = ppi + t_decay[orow];
    float p2  = fmaxf(ww2, sk);
    float e1b = expf(ww2 - p2), e2b = expf(sk - p2);
    out_x[orow]  = x[orow];
    out_aa[orow] = e1b * aai + e2b * sv;
    out_bb[orow] = e1b * bbi + e2b;
    out_pp[orow] = p2;
  }
}

// ---------- kernel 2: y = w_out @ rab, wave-per-row, rab staged in LDS ----------
__global__ void __launch_bounds__(BLK2) matvec_out_kernel(
    const float* __restrict__ w, const float* __restrict__ xin,
    float* __restrict__ y) {
  __shared__ f4 xs[DIM / 4];  // 16 KB
  const int t = threadIdx.x;
  const f4* x4 = (const f4*)xin;
#pragma unroll
  for (int k = 0; k < 4; ++k) xs[t + k * BLK2] = x4[t + k * BLK2];
  __syncthreads();

  const int wave = t >> 6, lane = t & 63;
  const int row = blockIdx.x * 4 + wave;
  const f4* wp = (const f4*)(w + (size_t)row * DIM);

  float acc = 0.f;
#pragma unroll
  for (int i = 0; i < 16; ++i) {
    f4 wv = __builtin_nontemporal_load(&wp[i * 64 + lane]);
    acc += dot4(wv, xs[i * 64 + lane]);
  }

#pragma unroll
  for (int off = 32; off > 0; off >>= 1) acc += __shfl_down(acc, off);
  if (lane == 0) y[row] = acc;
}

extern "C" void kernel_launch(void* const* d_in, const int* in_sizes, int n_in,
                              void* d_out, int out_size, void* d_ws, size_t ws_size,
                              hipStream_t stream) {
  const float* x       = (const float*)d_in[0];
  const float* sxx     = (const float*)d_in[1];
  const float* aa      = (const float*)d_in[2];
  const float* bb      = (const float*)d_in[3];
  const float* pp      = (const float*)d_in[4];
  const float* w_key   = (const float*)d_in[5];
  const float* w_val   = (const float*)d_in[6];
  const float* w_rec   = (const float*)d_in[7];
  const float* w_out   = (const float*)d_in[8];
  const float* t_decay = (const float*)d_in[9];
  const float* t_first = (const float*)d_in[10];
  const float* t_mix_k = (const float*)d_in[11];
  const float* t_mix_v = (const float*)d_in[12];
  const float* t_mix_r = (const float*)d_in[13];

  float* out    = (float*)d_out;
  float* y      = out;            // output 0
  float* out_x  = out + DIM;      // output 1 (new state_xx = x)
  float* out_aa = out + 2 * DIM;  // output 2
  float* out_bb = out + 3 * DIM;  // output 3
  float* out_pp = out + 4 * DIM;  // output 4

  float* rab = (float*)d_ws;      // 4096 floats

  fused3_kernel<<<DIM / RPB, BLK1, 0, stream>>>(
      x, sxx, t_mix_k, t_mix_v, t_mix_r, w_rec, w_key, w_val,
      aa, bb, pp, t_decay, t_first,
      rab, out_x, out_aa, out_bb, out_pp);
  matvec_out_kernel<<<DIM / 4, BLK2, 0, stream>>>(w_out, rab, y);
}